// Round 6
// baseline (1504.306 us; speedup 1.0000x reference)
//
#include <hip/hip_runtime.h>
#include <hip/hip_bf16.h>

// B=256, L=512, E=256, V=50000, C=5
#define EDIM 256
#define TWO_E 512
#define CDIM 5
#define NNODES 1023

__device__ __forceinline__ void project_one(const float* __restrict__ row,
                                            const float* __restrict__ P,
                                            const float* __restrict__ pb,
                                            float* __restrict__ out,
                                            long long obase, int lane) {
    float s0 = 0.f, s1 = 0.f, s2 = 0.f, s3 = 0.f, s4 = 0.f;
#pragma unroll
    for (int k = 0; k < 4; ++k) {
        int pe = lane + 64 * k;
        float v = row[pe];
        s0 = fmaf(v, P[0 * EDIM + pe], s0);
        s1 = fmaf(v, P[1 * EDIM + pe], s1);
        s2 = fmaf(v, P[2 * EDIM + pe], s2);
        s3 = fmaf(v, P[3 * EDIM + pe], s3);
        s4 = fmaf(v, P[4 * EDIM + pe], s4);
    }
#pragma unroll
    for (int off = 32; off; off >>= 1) {
        s0 += __shfl_xor(s0, off);
        s1 += __shfl_xor(s1, off);
        s2 += __shfl_xor(s2, off);
        s3 += __shfl_xor(s3, off);
        s4 += __shfl_xor(s4, off);
    }
    if (lane == 0) {
        // d_out is FLOAT32 (reference output dtype) — this was the 5-round bug.
        out[obase + 0] = s0 + pb[0];
        out[obase + 1] = s1 + pb[1];
        out[obase + 2] = s2 + pb[2];
        out[obase + 3] = s3 + pb[3];
        out[obase + 4] = s4 + pb[4];
    }
}

template<int NPAR>
__device__ __forceinline__ void do_level(float* lds, const float* __restrict__ W,
                                         float bias, int e, int wid, int lane,
                                         const float* __restrict__ P,
                                         const float* __restrict__ pb,
                                         float* __restrict__ out,
                                         long long obase) {
    float acc[NPAR];
#pragma unroll
    for (int p = 0; p < NPAR; ++p) acc[p] = 0.f;
    const float4* W4 = (const float4*)(W + (long long)e * TWO_E);
    for (int f4 = 0; f4 < TWO_E / 4; ++f4) {
        float4 wv = W4[f4];
#pragma unroll
        for (int p = 0; p < NPAR; ++p) {
            float4 cv = *(const float4*)(lds + p * TWO_E + 4 * f4);  // wave-uniform broadcast
            acc[p] = fmaf(wv.x, cv.x, acc[p]);
            acc[p] = fmaf(wv.y, cv.y, acc[p]);
            acc[p] = fmaf(wv.z, cv.z, acc[p]);
            acc[p] = fmaf(wv.w, cv.w, acc[p]);
        }
    }
    __syncthreads();  // all child reads complete before overwrite
#pragma unroll
    for (int p = 0; p < NPAR; ++p) lds[p * EDIM + e] = fmaxf(acc[p] + bias, 0.f);
    __syncthreads();
    for (int r = wid; r < NPAR; r += 4)
        project_one(lds + r * EDIM, P, pb, out, obase + (long long)r * CDIM, lane);
}

// One block = one 32-leaf subtree. Leaves + levels 1..5 compose+projection.
__global__ __launch_bounds__(256) void k_tree_lo(
    const int* __restrict__ words, const float* __restrict__ emb,
    const float* __restrict__ W, const float* __restrict__ bvec,
    const float* __restrict__ P, const float* __restrict__ pb,
    float* __restrict__ out, float* __restrict__ h5) {
    __shared__ alignas(16) float lds[32 * EDIM];  // 32 KiB
    const int tid = threadIdx.x, lane = tid & 63, wid = tid >> 6;
    const long long gp0 = (long long)blockIdx.x * 16;  // level-1 flat base (b*256 + n1)
    const long long leaf0 = 2 * gp0;                   // leaf flat base (b*512 + pos)
    const long long bI = gp0 >> 8;
    const int g = (int)(gp0 & 255);

    for (int r = 0; r < 32; ++r) {
        int wd = words[leaf0 + r];
        lds[r * EDIM + tid] = fmaxf(emb[(long long)wd * EDIM + tid], 0.f);
    }
    __syncthreads();

    const long long base = bI * NNODES;
    for (int r = wid; r < 32; r += 4)
        project_one(lds + r * EDIM, P, pb, out, (base + 2 * g + r) * CDIM, lane);

    const int e = tid;
    const float bias = bvec[e];
    do_level<16>(lds, W, bias, e, wid, lane, P, pb, out, (base + 512 + g) * CDIM);
    do_level<8>(lds, W, bias, e, wid, lane, P, pb, out, (base + 768 + (g >> 1)) * CDIM);
    do_level<4>(lds, W, bias, e, wid, lane, P, pb, out, (base + 896 + (g >> 2)) * CDIM);
    do_level<2>(lds, W, bias, e, wid, lane, P, pb, out, (base + 960 + (g >> 3)) * CDIM);
    do_level<1>(lds, W, bias, e, wid, lane, P, pb, out, (base + 992 + (g >> 4)) * CDIM);

    h5[((bI << 4) + (g >> 4)) * EDIM + e] = lds[e];  // f32 L5 row
}

// One block per batch: levels 6..9 from the 16 L5 rows.
__global__ __launch_bounds__(256) void k_tree_hi(
    const float* __restrict__ h5, const float* __restrict__ W,
    const float* __restrict__ bvec, const float* __restrict__ P,
    const float* __restrict__ pb, float* __restrict__ out) {
    __shared__ alignas(16) float lds[16 * EDIM];
    const int tid = threadIdx.x, lane = tid & 63, wid = tid >> 6;
    const long long b = blockIdx.x;
    for (int i = tid; i < 16 * EDIM; i += 256)
        lds[i] = h5[b * 16 * EDIM + i];
    __syncthreads();

    const int e = tid;
    const float bias = bvec[e];
    const long long base = b * NNODES;
    do_level<8>(lds, W, bias, e, wid, lane, P, pb, out, (base + 1008) * CDIM);
    do_level<4>(lds, W, bias, e, wid, lane, P, pb, out, (base + 1016) * CDIM);
    do_level<2>(lds, W, bias, e, wid, lane, P, pb, out, (base + 1020) * CDIM);
    do_level<1>(lds, W, bias, e, wid, lane, P, pb, out, (base + 1022) * CDIM);
}

extern "C" void kernel_launch(void* const* d_in, const int* in_sizes, int n_in,
                              void* d_out, int out_size, void* d_ws, size_t ws_size,
                              hipStream_t stream) {
    const int* words = (const int*)d_in[0];
    const float* emb = (const float*)d_in[1];
    const float* W = (const float*)d_in[2];
    const float* bv = (const float*)d_in[3];
    const float* P = (const float*)d_in[4];
    const float* pb = (const float*)d_in[5];
    float* out = (float*)d_out;  // f32 output — the round-0..5 bug was bf16 here

    float* h5 = (float*)d_ws;  // 4096 x 256 f32 = 4 MiB

    k_tree_lo<<<4096, 256, 0, stream>>>(words, emb, W, bv, P, pb, out, h5);
    k_tree_hi<<<256, 256, 0, stream>>>(h5, W, bv, P, pb, out);
}